// Round 1
// baseline (507.586 us; speedup 1.0000x reference)
//
#include <hip/hip_runtime.h>
#include <math.h>

#define Bn 8
#define CIN 64
#define HH 32
#define WW 32
#define HW 1024
#define CQKV 192
#define NHh 4
#define DKHd 16
#define DVHd 16

// ---------------------------------------------------------------------------
// Kernel 1: fused 3x3 conv for all 3 streams.
// grid: (24 co-tiles of 8, 8 batch, 3 streams), block 256.
// out layout: qkv[s][b][ch(192)][1024], q channels (<64) pre-scaled by 0.25.
// ---------------------------------------------------------------------------
__global__ __launch_bounds__(256) void conv_qkv_kernel(
    const float* __restrict__ x1, const float* __restrict__ x2,
    const float* __restrict__ x12,
    const float* __restrict__ w1, const float* __restrict__ w2,
    const float* __restrict__ w12,
    const float* __restrict__ b1, const float* __restrict__ b2,
    const float* __restrict__ b12,
    float* __restrict__ qkv)
{
    __shared__ float xp[34 * 34];
    const int s   = blockIdx.z;
    const int b   = blockIdx.y;
    const int co0 = blockIdx.x * 8;
    const int tid = threadIdx.x;

    const float* x  = (s == 0) ? x1 : (s == 1) ? x2 : x12;
    const float* w  = (s == 0) ? w1 : (s == 1) ? w2 : w12;
    const float* bi = (s == 0) ? b1 : (s == 1) ? b2 : b12;

    const float* xb = x + (size_t)b * CIN * HW;

    float acc[8][4];
    #pragma unroll
    for (int c = 0; c < 8; ++c)
        #pragma unroll
        for (int p = 0; p < 4; ++p) acc[c][p] = 0.f;

    for (int ci = 0; ci < CIN; ++ci) {
        __syncthreads();
        for (int e = tid; e < 34 * 34; e += 256) {
            int yy = e / 34, xx = e % 34;
            int gy = yy - 1, gx = xx - 1;
            float v = 0.f;
            if ((unsigned)gy < 32u && (unsigned)gx < 32u)
                v = xb[ci * HW + gy * 32 + gx];
            xp[e] = v;
        }
        __syncthreads();

        float w9[8][9];
        #pragma unroll
        for (int c = 0; c < 8; ++c)
            #pragma unroll
            for (int k = 0; k < 9; ++k)
                w9[c][k] = w[((size_t)(co0 + c) * CIN + ci) * 9 + k];

        #pragma unroll
        for (int p = 0; p < 4; ++p) {
            const int pix = tid + p * 256;
            const int y = pix >> 5, xc = pix & 31;
            float xv[9];
            #pragma unroll
            for (int ky = 0; ky < 3; ++ky)
                #pragma unroll
                for (int kx = 0; kx < 3; ++kx)
                    xv[ky * 3 + kx] = xp[(y + ky) * 34 + (xc + kx)];
            #pragma unroll
            for (int c = 0; c < 8; ++c) {
                float a = acc[c][p];
                #pragma unroll
                for (int k = 0; k < 9; ++k) a = fmaf(w9[c][k], xv[k], a);
                acc[c][p] = a;
            }
        }
    }

    float* outb = qkv + ((size_t)s * Bn + b) * CQKV * HW;
    #pragma unroll
    for (int c = 0; c < 8; ++c) {
        const int ch = co0 + c;
        const float bv = bi[ch];
        const float scale = (ch < 64) ? 0.25f : 1.f;  // DKH^-0.5 on q only
        #pragma unroll
        for (int p = 0; p < 4; ++p) {
            const int pix = tid + p * 256;
            outb[(size_t)ch * HW + pix] = (acc[c][p] + bv) * scale;
        }
    }
}

// ---------------------------------------------------------------------------
// Kernel 2: rel-logit precompute.
// qrw[bh][m][i] = sum_d q1[b,h,d,i] * rel_w[m,d]   (m = 0..62), same for qrh.
// grid: (63 m, 32 bh), block 256 (4 i per thread).
// ---------------------------------------------------------------------------
__global__ __launch_bounds__(256) void qrel_kernel(
    const float* __restrict__ qkv,      // stream-0 base (q1 scaled)
    const float* __restrict__ relw, const float* __restrict__ relh,
    float* __restrict__ qrw, float* __restrict__ qrh)
{
    const int m  = blockIdx.x;          // 0..62
    const int bh = blockIdx.y;          // b*4+h
    const int b  = bh >> 2, h = bh & 3;

    float ww[16], wh[16];
    #pragma unroll
    for (int d = 0; d < 16; ++d) {
        ww[d] = relw[m * 16 + d];
        wh[d] = relh[m * 16 + d];
    }
    const float* qb = qkv + ((size_t)b * CQKV + h * 16) * HW;
    for (int i = threadIdx.x; i < HW; i += 256) {
        float sw = 0.f, sh = 0.f;
        #pragma unroll
        for (int d = 0; d < 16; ++d) {
            const float qv = qb[(size_t)d * HW + i];
            sw = fmaf(qv, ww[d], sw);
            sh = fmaf(qv, wh[d], sh);
        }
        qrw[((size_t)bh * 64 + m) * HW + i] = sw;
        qrh[((size_t)bh * 64 + m) * HW + i] = sh;
    }
}

// ---------------------------------------------------------------------------
// Kernel 3: fused logits + softmax + PV, flash-style, all 3 streams.
// grid: (4 q-chunks, 32 bh, 3 streams), block 256 (1 query per thread).
// S=0: K=k12, V=v1, + rel terms.  S=1: K=k12, V=v2.  S=2: K=k1-k2, V=v12.
// o layout: [s][b][h][i][d] (== reference (B,NH,HW,DVH) per stream).
// ---------------------------------------------------------------------------
__global__ __launch_bounds__(256, 1) void attn_kernel(
    const float* __restrict__ qkv,
    const float* __restrict__ qrw, const float* __restrict__ qrh,
    float* __restrict__ o)
{
    __shared__ float Ks[16 * HW];   // [j][d]
    __shared__ float Vs[16 * HW];   // [j][d]

    const int S   = blockIdx.z;
    const int bh  = blockIdx.y;
    const int b   = bh >> 2, h = bh & 3;
    const int tid = threadIdx.x;
    const size_t SS = (size_t)Bn * CQKV * HW;

    const float* qsrc = qkv + S * SS + ((size_t)b * CQKV + h * 16) * HW;
    const float* vsrc = qkv + S * SS + ((size_t)b * CQKV + 128 + h * 16) * HW;
    const float* ksrc1;
    const float* ksrc2;
    if (S == 2) {
        ksrc1 = qkv + 0 * SS + ((size_t)b * CQKV + 64 + h * 16) * HW;
        ksrc2 = qkv + 1 * SS + ((size_t)b * CQKV + 64 + h * 16) * HW;
    } else {
        ksrc1 = qkv + 2 * SS + ((size_t)b * CQKV + 64 + h * 16) * HW;
        ksrc2 = ksrc1;
    }

    // Stage K,V into LDS (coalesced global reads, transpose to [j][d]).
    for (int g = tid; g < 16 * HW; g += 256) {
        const int d = g >> 10, j = g & 1023;
        float kv = ksrc1[(size_t)d * HW + j];
        if (S == 2) kv -= ksrc2[(size_t)d * HW + j];
        Ks[j * 16 + d] = kv;
        Vs[j * 16 + d] = vsrc[(size_t)d * HW + j];
    }
    __syncthreads();

    const int i  = blockIdx.x * 256 + tid;
    const int y1 = i >> 5, x1 = i & 31;

    float q[16];
    #pragma unroll
    for (int d = 0; d < 16; ++d) q[d] = qsrc[(size_t)d * HW + i];

    // rel-w row cache: entry t corresponds to x2 = t  (m = x2 - x1 + 31).
    float rw[32];
    if (S == 0) {
        #pragma unroll
        for (int t = 0; t < 32; ++t)
            rw[t] = qrw[((size_t)bh * 64 + (31 - x1 + t)) * HW + i];
    }

    float mval = -1e30f, l = 0.f;
    float acc[16];
    #pragma unroll
    for (int d = 0; d < 16; ++d) acc[d] = 0.f;

    for (int y2 = 0; y2 < 32; ++y2) {
        float rh = 0.f;
        if (S == 0)
            rh = qrh[((size_t)bh * 64 + (y2 - y1 + 31)) * HW + i];

        float srow[32];
        #pragma unroll
        for (int x2 = 0; x2 < 32; ++x2) {
            const int j = (y2 << 5) | x2;
            float sv = 0.f;
            #pragma unroll
            for (int d = 0; d < 16; ++d)
                sv = fmaf(q[d], Ks[j * 16 + d], sv);
            if (S == 0) sv += rh + rw[x2];
            srow[x2] = sv;
        }

        float rmax = srow[0];
        #pragma unroll
        for (int x2 = 1; x2 < 32; ++x2) rmax = fmaxf(rmax, srow[x2]);
        const float mnew = fmaxf(mval, rmax);
        const float f = __expf(mval - mnew);
        l *= f;
        #pragma unroll
        for (int d = 0; d < 16; ++d) acc[d] *= f;

        #pragma unroll
        for (int x2 = 0; x2 < 32; ++x2) {
            const int j = (y2 << 5) | x2;
            const float p = __expf(srow[x2] - mnew);
            l += p;
            #pragma unroll
            for (int d = 0; d < 16; ++d)
                acc[d] = fmaf(p, Vs[j * 16 + d], acc[d]);
        }
        mval = mnew;
    }

    const float inv = 1.f / l;
    float* op = o + ((((size_t)S * Bn + b) * NHh + h) * HW + i) * 16;
    #pragma unroll
    for (int d = 0; d < 16; ++d) op[d] = acc[d] * inv;
}

// ---------------------------------------------------------------------------
// Kernel 4: 1x1 output conv. The reference's "raw reshape" of (HW,DVH) into
// (DVH,H,W) means conv-input channel c at pixel p is flat offset c*1024+p of
// the o buffer. grid: (64 co, 24 sb), block 256 (4 px per thread).
// ---------------------------------------------------------------------------
__global__ __launch_bounds__(256) void out_conv_kernel(
    const float* __restrict__ o, const float* __restrict__ wout,
    const float* __restrict__ bout, float* __restrict__ out)
{
    const int co = blockIdx.x;
    const int sb = blockIdx.y;      // s*8 + b
    const int tid = threadIdx.x;
    const float* ob = o + (size_t)sb * 64 * HW;

    float acc[4] = {0.f, 0.f, 0.f, 0.f};
    for (int c = 0; c < 64; ++c) {
        const float wv = wout[co * 64 + c];
        #pragma unroll
        for (int p = 0; p < 4; ++p)
            acc[p] = fmaf(wv, ob[(size_t)c * HW + tid + p * 256], acc[p]);
    }
    const float bv = bout[co];
    #pragma unroll
    for (int p = 0; p < 4; ++p)
        out[((size_t)sb * 64 + co) * HW + tid + p * 256] = acc[p] + bv;
}

// ---------------------------------------------------------------------------
extern "C" void kernel_launch(void* const* d_in, const int* in_sizes, int n_in,
                              void* d_out, int out_size, void* d_ws, size_t ws_size,
                              hipStream_t stream)
{
    const float* x1   = (const float*)d_in[0];
    const float* x2   = (const float*)d_in[1];
    const float* x12  = (const float*)d_in[2];
    const float* wq1  = (const float*)d_in[3];
    const float* bq1  = (const float*)d_in[4];
    const float* wq2  = (const float*)d_in[5];
    const float* bq2  = (const float*)d_in[6];
    const float* wq12 = (const float*)d_in[7];
    const float* bq12 = (const float*)d_in[8];
    const float* wout = (const float*)d_in[9];
    const float* bout = (const float*)d_in[10];
    const float* relw = (const float*)d_in[11];
    const float* relh = (const float*)d_in[12];

    float* ws  = (float*)d_ws;
    float* qkv = ws;                                   // 3*8*192*1024      = 4,718,592 f
    float* qrw = qkv + (size_t)3 * Bn * CQKV * HW;     // 32*64*1024        = 2,097,152 f
    float* qrh = qrw + (size_t)32 * 64 * HW;           // 2,097,152 f
    float* o   = qrh + (size_t)32 * 64 * HW;           // 3*8*4*1024*16     = 1,572,864 f
                                                       // total ~40 MB

    conv_qkv_kernel<<<dim3(24, 8, 3), 256, 0, stream>>>(
        x1, x2, x12, wq1, wq2, wq12, bq1, bq2, bq12, qkv);

    qrel_kernel<<<dim3(63, 32), 256, 0, stream>>>(qkv, relw, relh, qrw, qrh);

    attn_kernel<<<dim3(4, 32, 3), 256, 0, stream>>>(qkv, qrw, qrh, o);

    out_conv_kernel<<<dim3(64, 24), 256, 0, stream>>>(o, wout, bout, (float*)d_out);
}

// Round 3
// 282.398 us; speedup vs baseline: 1.7974x; 1.7974x over previous
//
#include <hip/hip_runtime.h>
#include <math.h>

#define Bn 8
#define CIN 64
#define HH 32
#define WW 32
#define HW 1024
#define CQKV 192
#define NHh 4
#define DKHd 16
#define DVHd 16

typedef _Float16 half4_t __attribute__((ext_vector_type(4)));
typedef _Float16 half8_t __attribute__((ext_vector_type(8)));
typedef float f32x4 __attribute__((ext_vector_type(4)));

// ---------------------------------------------------------------------------
// Kernel 1: fused 3x3 conv for all 3 streams (unchanged from round 0).
// ---------------------------------------------------------------------------
__global__ __launch_bounds__(256) void conv_qkv_kernel(
    const float* __restrict__ x1, const float* __restrict__ x2,
    const float* __restrict__ x12,
    const float* __restrict__ w1, const float* __restrict__ w2,
    const float* __restrict__ w12,
    const float* __restrict__ b1, const float* __restrict__ b2,
    const float* __restrict__ b12,
    float* __restrict__ qkv)
{
    __shared__ float xp[34 * 34];
    const int s   = blockIdx.z;
    const int b   = blockIdx.y;
    const int co0 = blockIdx.x * 8;
    const int tid = threadIdx.x;

    const float* x  = (s == 0) ? x1 : (s == 1) ? x2 : x12;
    const float* w  = (s == 0) ? w1 : (s == 1) ? w2 : w12;
    const float* bi = (s == 0) ? b1 : (s == 1) ? b2 : b12;

    const float* xb = x + (size_t)b * CIN * HW;

    float acc[8][4];
    #pragma unroll
    for (int c = 0; c < 8; ++c)
        #pragma unroll
        for (int p = 0; p < 4; ++p) acc[c][p] = 0.f;

    for (int ci = 0; ci < CIN; ++ci) {
        __syncthreads();
        for (int e = tid; e < 34 * 34; e += 256) {
            int yy = e / 34, xx = e % 34;
            int gy = yy - 1, gx = xx - 1;
            float v = 0.f;
            if ((unsigned)gy < 32u && (unsigned)gx < 32u)
                v = xb[ci * HW + gy * 32 + gx];
            xp[e] = v;
        }
        __syncthreads();

        float w9[8][9];
        #pragma unroll
        for (int c = 0; c < 8; ++c)
            #pragma unroll
            for (int k = 0; k < 9; ++k)
                w9[c][k] = w[((size_t)(co0 + c) * CIN + ci) * 9 + k];

        #pragma unroll
        for (int p = 0; p < 4; ++p) {
            const int pix = tid + p * 256;
            const int y = pix >> 5, xc = pix & 31;
            float xv[9];
            #pragma unroll
            for (int ky = 0; ky < 3; ++ky)
                #pragma unroll
                for (int kx = 0; kx < 3; ++kx)
                    xv[ky * 3 + kx] = xp[(y + ky) * 34 + (xc + kx)];
            #pragma unroll
            for (int c = 0; c < 8; ++c) {
                float a = acc[c][p];
                #pragma unroll
                for (int k = 0; k < 9; ++k) a = fmaf(w9[c][k], xv[k], a);
                acc[c][p] = a;
            }
        }
    }

    float* outb = qkv + ((size_t)s * Bn + b) * CQKV * HW;
    #pragma unroll
    for (int c = 0; c < 8; ++c) {
        const int ch = co0 + c;
        const float bv = bi[ch];
        const float scale = (ch < 64) ? 0.25f : 1.f;  // DKH^-0.5 on q only
        #pragma unroll
        for (int p = 0; p < 4; ++p) {
            const int pix = tid + p * 256;
            outb[(size_t)ch * HW + pix] = (acc[c][p] + bv) * scale;
        }
    }
}

// ---------------------------------------------------------------------------
// Kernel 2: rel-logit precompute (unchanged).
// ---------------------------------------------------------------------------
__global__ __launch_bounds__(256) void qrel_kernel(
    const float* __restrict__ qkv,
    const float* __restrict__ relw, const float* __restrict__ relh,
    float* __restrict__ qrw, float* __restrict__ qrh)
{
    const int m  = blockIdx.x;          // 0..62
    const int bh = blockIdx.y;          // b*4+h
    const int b  = bh >> 2, h = bh & 3;

    float ww[16], wh[16];
    #pragma unroll
    for (int d = 0; d < 16; ++d) {
        ww[d] = relw[m * 16 + d];
        wh[d] = relh[m * 16 + d];
    }
    const float* qb = qkv + ((size_t)b * CQKV + h * 16) * HW;
    for (int i = threadIdx.x; i < HW; i += 256) {
        float sw = 0.f, sh = 0.f;
        #pragma unroll
        for (int d = 0; d < 16; ++d) {
            const float qv = qb[(size_t)d * HW + i];
            sw = fmaf(qv, ww[d], sw);
            sh = fmaf(qv, wh[d], sh);
        }
        qrw[((size_t)bh * 64 + m) * HW + i] = sw;
        qrh[((size_t)bh * 64 + m) * HW + i] = sh;
    }
}

// ---------------------------------------------------------------------------
// Kernel 3: MFMA flash attention, f16 fragments.
// grid: (16 qblocks of 64, 32 bh, 3 streams), block 256 (4 waves x 16 queries).
//
// Swapped QK^T: S^T-tile = mfma_16x16x16f16(A=K-tile, B=Q-tile) so the D
// layout (col = lane&15 = QUERY, row = (lane>>4)*4+r = key-local) puts 4 key
// scores of ONE query in each lane. Max/sum reduce = shfl_xor(16) + (32).
// exp'd scores are exactly the B-fragment of the PV mfma:
//   O^T = mfma(A = V^T-tile (dv x key), B = P^T-tile (key x q), acc).
// K,V staged in LDS as pre-arranged fragments: frag(kt,lane) = 4 halves;
// half addr = (kt>>1)*512 + lane*8 + (kt&1)*4 -> hot-loop ds_read_b128
// (wave reads contiguous 1KB, conflict-free), staging ds_write_b64 conflict-
// free. LDS = 2 x 32KB = 64KB -> 2 blocks/CU (8 waves) vs round-0's 1 block.
// ---------------------------------------------------------------------------
__global__ __launch_bounds__(256, 2) void attn_mfma_kernel(
    const float* __restrict__ qkv,
    const float* __restrict__ qrw, const float* __restrict__ qrh,
    float* __restrict__ o)
{
    __shared__ _Float16 kf_lds[16384];   // 32 KB: K fragments
    __shared__ _Float16 vf_lds[16384];   // 32 KB: V fragments

    const int S   = blockIdx.z;
    const int bh  = blockIdx.y;
    const int b   = bh >> 2, hd = bh & 3;
    const int tid = threadIdx.x;
    const int w    = tid >> 6;
    const int lane = tid & 63;
    const int g    = lane >> 4;          // 4-lane group id (0..3)
    const int lq   = lane & 15;
    const size_t SS = (size_t)Bn * CQKV * HW;

    const float* qsrc = qkv + S * SS + ((size_t)b * CQKV + hd * 16) * HW;
    const float* vsrc = qkv + S * SS + ((size_t)b * CQKV + 128 + hd * 16) * HW;
    const float* k1p;
    const float* k2p;
    if (S == 2) {
        k1p = qkv + 0 * SS + ((size_t)b * CQKV + 64 + hd * 16) * HW;
        k2p = qkv + 1 * SS + ((size_t)b * CQKV + 64 + hd * 16) * HW;
    } else {
        k1p = qkv + 2 * SS + ((size_t)b * CQKV + 64 + hd * 16) * HW;
        k2p = k1p;
    }

    // ---- stage K,V as MFMA fragments (f32 global -> f16 LDS) -------------
    // frag element (kt, l):
    //   K: A-frag of S^T mfma: K[key = kt*16+(l&15)][d = (l>>4)*4 + j]
    //   V: A-frag of PV  mfma: V^T[dv = l&15][key = kt*16 + (l>>4)*4 + j]
    #pragma unroll 4
    for (int it = 0; it < 16; ++it) {
        const int idx = it * 256 + tid;          // 0..4095
        const int kt  = idx >> 6, l = idx & 63;
        const int row = l & 15;
        const int d0  = (l >> 4) * 4;
        const int lofs = (kt >> 1) * 512 + l * 8 + (kt & 1) * 4;  // half idx

        const int key = kt * 16 + row;
        half4_t kh;
        #pragma unroll
        for (int j = 0; j < 4; ++j) {
            float x = k1p[(size_t)(d0 + j) * HW + key];
            if (S == 2) x -= k2p[(size_t)(d0 + j) * HW + key];
            kh[j] = (_Float16)x;
        }
        *reinterpret_cast<half4_t*>(&kf_lds[lofs]) = kh;

        const f32x4 vv = *reinterpret_cast<const f32x4*>(
            &vsrc[(size_t)row * HW + kt * 16 + d0]);
        half4_t vh;
        #pragma unroll
        for (int j = 0; j < 4; ++j) vh[j] = (_Float16)vv[j];
        *reinterpret_cast<half4_t*>(&vf_lds[lofs]) = vh;
    }

    // ---- per-wave Q fragment + rel-w register cache -----------------------
    const int qb0 = blockIdx.x * 64 + w * 16;
    const int i   = qb0 + lq;                 // this lane's query
    const int x1  = i & 31, y1 = i >> 5;      // y1 uniform per wave

    half4_t qf;
    #pragma unroll
    for (int j = 0; j < 4; ++j)
        qf[j] = (_Float16)qsrc[(size_t)(g * 4 + j) * HW + i];

    float rwc0[4], rwc1[4];
    if (S == 0) {
        #pragma unroll
        for (int r = 0; r < 4; ++r) {
            rwc0[r] = qrw[((size_t)bh * 64 + (g * 4 + r      - x1 + 31)) * HW + i];
            rwc1[r] = qrw[((size_t)bh * 64 + (g * 4 + r + 16 - x1 + 31)) * HW + i];
        }
    }

    __syncthreads();

    f32x4 acc = {0.f, 0.f, 0.f, 0.f};
    float m = -1e30f, lsum = 0.f;
    const f32x4 zero4 = {0.f, 0.f, 0.f, 0.f};

    // ---- online-softmax sweep: 32 chunks x 32 keys ------------------------
    for (int c = 0; c < 32; ++c) {
        const half8_t kk = *reinterpret_cast<const half8_t*>(&kf_lds[c * 512 + lane * 8]);
        const half8_t vv = *reinterpret_cast<const half8_t*>(&vf_lds[c * 512 + lane * 8]);
        float rh = 0.f;
        if (S == 0)
            rh = qrh[((size_t)bh * 64 + (c - y1 + 31)) * HW + i];

        const half4_t ka = __builtin_shufflevector(kk, kk, 0, 1, 2, 3);
        const half4_t kb = __builtin_shufflevector(kk, kk, 4, 5, 6, 7);
        f32x4 s0 = __builtin_amdgcn_mfma_f32_16x16x16f16(ka, qf, zero4, 0, 0, 0);
        f32x4 s1 = __builtin_amdgcn_mfma_f32_16x16x16f16(kb, qf, zero4, 0, 0, 0);

        if (S == 0) {
            #pragma unroll
            for (int r = 0; r < 4; ++r) {
                s0[r] += rh + rwc0[r];
                s1[r] += rh + rwc1[r];
            }
        }

        float vmax = fmaxf(fmaxf(fmaxf(s0[0], s0[1]), fmaxf(s0[2], s0[3])),
                           fmaxf(fmaxf(s1[0], s1[1]), fmaxf(s1[2], s1[3])));
        vmax = fmaxf(vmax, __shfl_xor(vmax, 16));
        vmax = fmaxf(vmax, __shfl_xor(vmax, 32));

        const float mnew = fmaxf(m, vmax);
        const float fsc  = __expf(m - mnew);
        m = mnew;
        lsum *= fsc;
        acc *= fsc;

        half4_t pa, pb;
        #pragma unroll
        for (int r = 0; r < 4; ++r) {
            const float p0 = __expf(s0[r] - mnew);
            const float p1 = __expf(s1[r] - mnew);
            lsum += p0 + p1;
            pa[r] = (_Float16)p0;
            pb[r] = (_Float16)p1;
        }

        const half4_t va = __builtin_shufflevector(vv, vv, 0, 1, 2, 3);
        const half4_t vb = __builtin_shufflevector(vv, vv, 4, 5, 6, 7);
        acc = __builtin_amdgcn_mfma_f32_16x16x16f16(va, pa, acc, 0, 0, 0);
        acc = __builtin_amdgcn_mfma_f32_16x16x16f16(vb, pb, acc, 0, 0, 0);
    }

    lsum += __shfl_xor(lsum, 16);
    lsum += __shfl_xor(lsum, 32);
    const float inv = 1.f / lsum;

    // lane holds O[q = i][dv = g*4 + r], r=0..3 -> contiguous float4
    float* op = o + ((((size_t)S * Bn + b) * NHh + hd) * HW) * 16;
    f32x4 res;
    #pragma unroll
    for (int r = 0; r < 4; ++r) res[r] = acc[r] * inv;
    *reinterpret_cast<f32x4*>(&op[(size_t)i * 16 + g * 4]) = res;
}

// ---------------------------------------------------------------------------
// Kernel 4: 1x1 output conv (unchanged).
// ---------------------------------------------------------------------------
__global__ __launch_bounds__(256) void out_conv_kernel(
    const float* __restrict__ o, const float* __restrict__ wout,
    const float* __restrict__ bout, float* __restrict__ out)
{
    const int co = blockIdx.x;
    const int sb = blockIdx.y;      // s*8 + b
    const int tid = threadIdx.x;
    const float* ob = o + (size_t)sb * 64 * HW;

    float acc[4] = {0.f, 0.f, 0.f, 0.f};
    for (int c = 0; c < 64; ++c) {
        const float wv = wout[co * 64 + c];
        #pragma unroll
        for (int p = 0; p < 4; ++p)
            acc[p] = fmaf(wv, ob[(size_t)c * HW + tid + p * 256], acc[p]);
    }
    const float bv = bout[co];
    #pragma unroll
    for (int p = 0; p < 4; ++p)
        out[((size_t)sb * 64 + co) * HW + tid + p * 256] = acc[p] + bv;
}

// ---------------------------------------------------------------------------
extern "C" void kernel_launch(void* const* d_in, const int* in_sizes, int n_in,
                              void* d_out, int out_size, void* d_ws, size_t ws_size,
                              hipStream_t stream)
{
    const float* x1   = (const float*)d_in[0];
    const float* x2   = (const float*)d_in[1];
    const float* x12  = (const float*)d_in[2];
    const float* wq1  = (const float*)d_in[3];
    const float* bq1  = (const float*)d_in[4];
    const float* wq2  = (const float*)d_in[5];
    const float* bq2  = (const float*)d_in[6];
    const float* wq12 = (const float*)d_in[7];
    const float* bq12 = (const float*)d_in[8];
    const float* wout = (const float*)d_in[9];
    const float* bout = (const float*)d_in[10];
    const float* relw = (const float*)d_in[11];
    const float* relh = (const float*)d_in[12];

    float* ws  = (float*)d_ws;
    float* qkv = ws;                                   // 3*8*192*1024
    float* qrw = qkv + (size_t)3 * Bn * CQKV * HW;     // 32*64*1024
    float* qrh = qrw + (size_t)32 * 64 * HW;
    float* o   = qrh + (size_t)32 * 64 * HW;           // 3*8*4*1024*16

    conv_qkv_kernel<<<dim3(24, 8, 3), 256, 0, stream>>>(
        x1, x2, x12, wq1, wq2, wq12, bq1, bq2, bq12, qkv);

    qrel_kernel<<<dim3(63, 32), 256, 0, stream>>>(qkv, relw, relh, qrw, qrh);

    attn_mfma_kernel<<<dim3(16, 32, 3), 256, 0, stream>>>(qkv, qrw, qrh, o);

    out_conv_kernel<<<dim3(64, 24), 256, 0, stream>>>(o, wout, bout, (float*)d_out);
}

// Round 4
// 139.244 us; speedup vs baseline: 3.6453x; 2.0281x over previous
//
#include <hip/hip_runtime.h>
#include <math.h>

#define Bn 8
#define CIN 64
#define HH 32
#define WW 32
#define HW 1024
#define CQKV 192
#define NHh 4
#define DKHd 16
#define DVHd 16

typedef _Float16 half4_t __attribute__((ext_vector_type(4)));
typedef _Float16 half8_t __attribute__((ext_vector_type(8)));
typedef float f32x4 __attribute__((ext_vector_type(4)));

// ---------------------------------------------------------------------------
// Prep A: x (f32, [sb][ci][32][32]) -> xt (f16, [sb][34][34][64]) zero-padded.
// grid (24 sb, 8 ci-groups), block 256.
// ---------------------------------------------------------------------------
__global__ __launch_bounds__(256) void prep_xt_kernel(
    const float* __restrict__ x1, const float* __restrict__ x2,
    const float* __restrict__ x12, _Float16* __restrict__ xt)
{
    const int sb = blockIdx.x;           // s*8 + b
    const int s  = sb >> 3, b = sb & 7;
    const int ci0 = blockIdx.y * 8;
    const float* x = (s == 0) ? x1 : (s == 1) ? x2 : x12;
    const float* xb = x + (size_t)b * CIN * HW;

    for (int pos = threadIdx.x; pos < 34 * 34; pos += 256) {
        const int row = pos / 34, col = pos % 34;
        const int gy = row - 1, gx = col - 1;
        half8_t v;
        if ((unsigned)gy < 32u && (unsigned)gx < 32u) {
            #pragma unroll
            for (int j = 0; j < 8; ++j)
                v[j] = (_Float16)xb[(size_t)(ci0 + j) * HW + gy * 32 + gx];
        } else {
            #pragma unroll
            for (int j = 0; j < 8; ++j) v[j] = (_Float16)0.f;
        }
        *reinterpret_cast<half8_t*>(&xt[((size_t)sb * 1156 + pos) * 64 + ci0]) = v;
    }
}

// ---------------------------------------------------------------------------
// Prep B: weights -> A-fragment layout wf[s][ct(12)][ks(36)][lane(64)][4] f16,
// with 0.25 q-scale folded in (co<64). grid 324, block 256.
// k ordering: k = tap*64 + ci  (tap = ky*3+kx).
// ---------------------------------------------------------------------------
__global__ __launch_bounds__(256) void prep_wf_kernel(
    const float* __restrict__ w1, const float* __restrict__ w2,
    const float* __restrict__ w12, _Float16* __restrict__ wf)
{
    const int f = blockIdx.x * 256 + threadIdx.x;   // 82944 frags
    if (f >= 3 * 12 * 36 * 64) return;
    const int lane = f & 63;
    int r = f >> 6;
    const int ks = r % 36; r /= 36;
    const int ct = r % 12; const int s = r / 12;
    const float* w = (s == 0) ? w1 : (s == 1) ? w2 : w12;

    const int tap = ks >> 2;
    const int ci_b = (ks & 3) * 16 + (lane >> 4) * 4;
    const int co = ct * 16 + (lane & 15);
    const float scale = (co < 64) ? 0.25f : 1.f;

    half4_t v;
    #pragma unroll
    for (int j = 0; j < 4; ++j)
        v[j] = (_Float16)(w[((size_t)co * 64 + ci_b + j) * 9 + tap] * scale);
    *reinterpret_cast<half4_t*>(&wf[(size_t)f * 4]) = v;
}

// ---------------------------------------------------------------------------
// Kernel 1: implicit-GEMM 3x3 conv via MFMA.
// grid (16 px-strips of 64, 8 b, 3 s), block 256 = 4 waves.
// Wave w: co-tiles {3w..3w+2} (48 co) x 4 px-tiles (64 px), K = 576.
// LDS: strip input window [4 rows][34 cols][64 ci] f16, XOR-swizzled so both
// staging ds_write_b64 and B-frag ds_read_b64 are bank-conflict-free.
// ---------------------------------------------------------------------------
__global__ __launch_bounds__(256) void conv_mfma_kernel(
    const _Float16* __restrict__ xt, const _Float16* __restrict__ wf,
    const float* __restrict__ b1, const float* __restrict__ b2,
    const float* __restrict__ b12, float* __restrict__ qkv)
{
    __shared__ _Float16 xs[8704];        // 4*34*64
    const int strip = blockIdx.x;
    const int b = blockIdx.y, s = blockIdx.z;
    const int sb = s * Bn + b;
    const int tid = threadIdx.x;
    const int w = tid >> 6, lane = tid & 63, g = lane >> 4, lq = lane & 15;
    const int y0 = strip * 2;

    // ---- stage strip window (contiguous in xt) into swizzled LDS ---------
    const half4_t* src = reinterpret_cast<const half4_t*>(
        xt + ((size_t)sb * 1156 + y0 * 34) * 64);
    for (int c = tid; c < 2176; c += 256) {            // chunks of 4 halves
        const int cic = c & 15;
        const int colrow = c >> 4;                     // ry*34 + xx
        const int xx = colrow % 34;
        const int lofs = colrow * 64 + ((cic ^ (xx & 15)) << 2);
        *reinterpret_cast<half4_t*>(&xs[lofs]) = src[c];
    }
    __syncthreads();

    f32x4 acc[3][4];
    #pragma unroll
    for (int cc = 0; cc < 3; ++cc)
        #pragma unroll
        for (int t = 0; t < 4; ++t) acc[cc][t] = (f32x4){0.f, 0.f, 0.f, 0.f};

    const _Float16* wfs = wf + ((size_t)(s * 12 + w * 3) * 36) * 256;

    #pragma unroll
    for (int tap = 0; tap < 9; ++tap) {
        const int ky = tap / 3, kx = tap % 3;
        #pragma unroll
        for (int sub = 0; sub < 4; ++sub) {
            const int ks = tap * 4 + sub;
            half4_t af[3];
            #pragma unroll
            for (int cc = 0; cc < 3; ++cc)
                af[cc] = *reinterpret_cast<const half4_t*>(
                    &wfs[((size_t)cc * 36 + ks) * 256 + lane * 4]);
            half4_t bf[4];
            #pragma unroll
            for (int t = 0; t < 4; ++t) {
                const int ry = (t >> 1) + ky;
                const int xx = (t & 1) * 16 + lq + kx;
                const int cichunk = sub * 4 + g;
                bf[t] = *reinterpret_cast<const half4_t*>(
                    &xs[(ry * 34 + xx) * 64 + ((cichunk ^ (xx & 15)) << 2)]);
            }
            #pragma unroll
            for (int cc = 0; cc < 3; ++cc)
                #pragma unroll
                for (int t = 0; t < 4; ++t)
                    acc[cc][t] = __builtin_amdgcn_mfma_f32_16x16x16f16(
                        af[cc], bf[t], acc[cc][t], 0, 0, 0);
        }
    }

    // ---- epilogue: bias (+0.25 scale on q-channel bias), store ------------
    const float* bi = (s == 0) ? b1 : (s == 1) ? b2 : b12;
    float* outb = qkv + (size_t)sb * CQKV * HW;
    #pragma unroll
    for (int cc = 0; cc < 3; ++cc) {
        const int ct = w * 3 + cc;
        const float bsc = (ct < 4) ? 0.25f : 1.f;
        const f32x4 bv4 = *reinterpret_cast<const f32x4*>(&bi[ct * 16 + g * 4]);
        #pragma unroll
        for (int t = 0; t < 4; ++t) {
            const int px = strip * 64 + t * 16 + lq;
            #pragma unroll
            for (int r = 0; r < 4; ++r) {
                const int ch = ct * 16 + g * 4 + r;
                outb[(size_t)ch * HW + px] = acc[cc][t][r] + bsc * bv4[r];
            }
        }
    }
}

// ---------------------------------------------------------------------------
// Kernel 2: rel-logit precompute (unchanged).
// ---------------------------------------------------------------------------
__global__ __launch_bounds__(256) void qrel_kernel(
    const float* __restrict__ qkv,
    const float* __restrict__ relw, const float* __restrict__ relh,
    float* __restrict__ qrw, float* __restrict__ qrh)
{
    const int m  = blockIdx.x;          // 0..62
    const int bh = blockIdx.y;          // b*4+h
    const int b  = bh >> 2, h = bh & 3;

    float ww[16], wh[16];
    #pragma unroll
    for (int d = 0; d < 16; ++d) {
        ww[d] = relw[m * 16 + d];
        wh[d] = relh[m * 16 + d];
    }
    const float* qb = qkv + ((size_t)b * CQKV + h * 16) * HW;
    for (int i = threadIdx.x; i < HW; i += 256) {
        float sw = 0.f, sh = 0.f;
        #pragma unroll
        for (int d = 0; d < 16; ++d) {
            const float qv = qb[(size_t)d * HW + i];
            sw = fmaf(qv, ww[d], sw);
            sh = fmaf(qv, wh[d], sh);
        }
        qrw[((size_t)bh * 64 + m) * HW + i] = sw;
        qrh[((size_t)bh * 64 + m) * HW + i] = sh;
    }
}

// ---------------------------------------------------------------------------
// Kernel 3: MFMA flash attention (unchanged from round 2).
// ---------------------------------------------------------------------------
__global__ __launch_bounds__(256, 2) void attn_mfma_kernel(
    const float* __restrict__ qkv,
    const float* __restrict__ qrw, const float* __restrict__ qrh,
    float* __restrict__ o)
{
    __shared__ _Float16 kf_lds[16384];   // 32 KB: K fragments
    __shared__ _Float16 vf_lds[16384];   // 32 KB: V fragments

    const int S   = blockIdx.z;
    const int bh  = blockIdx.y;
    const int b   = bh >> 2, hd = bh & 3;
    const int tid = threadIdx.x;
    const int w    = tid >> 6;
    const int lane = tid & 63;
    const int g    = lane >> 4;
    const int lq   = lane & 15;
    const size_t SS = (size_t)Bn * CQKV * HW;

    const float* qsrc = qkv + S * SS + ((size_t)b * CQKV + hd * 16) * HW;
    const float* vsrc = qkv + S * SS + ((size_t)b * CQKV + 128 + hd * 16) * HW;
    const float* k1p;
    const float* k2p;
    if (S == 2) {
        k1p = qkv + 0 * SS + ((size_t)b * CQKV + 64 + hd * 16) * HW;
        k2p = qkv + 1 * SS + ((size_t)b * CQKV + 64 + hd * 16) * HW;
    } else {
        k1p = qkv + 2 * SS + ((size_t)b * CQKV + 64 + hd * 16) * HW;
        k2p = k1p;
    }

    #pragma unroll 4
    for (int it = 0; it < 16; ++it) {
        const int idx = it * 256 + tid;
        const int kt  = idx >> 6, l = idx & 63;
        const int row = l & 15;
        const int d0  = (l >> 4) * 4;
        const int lofs = (kt >> 1) * 512 + l * 8 + (kt & 1) * 4;

        const int key = kt * 16 + row;
        half4_t kh;
        #pragma unroll
        for (int j = 0; j < 4; ++j) {
            float x = k1p[(size_t)(d0 + j) * HW + key];
            if (S == 2) x -= k2p[(size_t)(d0 + j) * HW + key];
            kh[j] = (_Float16)x;
        }
        *reinterpret_cast<half4_t*>(&kf_lds[lofs]) = kh;

        const f32x4 vv = *reinterpret_cast<const f32x4*>(
            &vsrc[(size_t)row * HW + kt * 16 + d0]);
        half4_t vh;
        #pragma unroll
        for (int j = 0; j < 4; ++j) vh[j] = (_Float16)vv[j];
        *reinterpret_cast<half4_t*>(&vf_lds[lofs]) = vh;
    }

    const int qb0 = blockIdx.x * 64 + w * 16;
    const int i   = qb0 + lq;
    const int x1  = i & 31, y1 = i >> 5;

    half4_t qf;
    #pragma unroll
    for (int j = 0; j < 4; ++j)
        qf[j] = (_Float16)qsrc[(size_t)(g * 4 + j) * HW + i];

    float rwc0[4], rwc1[4];
    if (S == 0) {
        #pragma unroll
        for (int r = 0; r < 4; ++r) {
            rwc0[r] = qrw[((size_t)bh * 64 + (g * 4 + r      - x1 + 31)) * HW + i];
            rwc1[r] = qrw[((size_t)bh * 64 + (g * 4 + r + 16 - x1 + 31)) * HW + i];
        }
    }

    __syncthreads();

    f32x4 acc = {0.f, 0.f, 0.f, 0.f};
    float m = -1e30f, lsum = 0.f;
    const f32x4 zero4 = {0.f, 0.f, 0.f, 0.f};

    for (int c = 0; c < 32; ++c) {
        const half8_t kk = *reinterpret_cast<const half8_t*>(&kf_lds[c * 512 + lane * 8]);
        const half8_t vv = *reinterpret_cast<const half8_t*>(&vf_lds[c * 512 + lane * 8]);
        float rh = 0.f;
        if (S == 0)
            rh = qrh[((size_t)bh * 64 + (c - y1 + 31)) * HW + i];

        const half4_t ka = __builtin_shufflevector(kk, kk, 0, 1, 2, 3);
        const half4_t kb = __builtin_shufflevector(kk, kk, 4, 5, 6, 7);
        f32x4 s0 = __builtin_amdgcn_mfma_f32_16x16x16f16(ka, qf, zero4, 0, 0, 0);
        f32x4 s1 = __builtin_amdgcn_mfma_f32_16x16x16f16(kb, qf, zero4, 0, 0, 0);

        if (S == 0) {
            #pragma unroll
            for (int r = 0; r < 4; ++r) {
                s0[r] += rh + rwc0[r];
                s1[r] += rh + rwc1[r];
            }
        }

        float vmax = fmaxf(fmaxf(fmaxf(s0[0], s0[1]), fmaxf(s0[2], s0[3])),
                           fmaxf(fmaxf(s1[0], s1[1]), fmaxf(s1[2], s1[3])));
        vmax = fmaxf(vmax, __shfl_xor(vmax, 16));
        vmax = fmaxf(vmax, __shfl_xor(vmax, 32));

        const float mnew = fmaxf(m, vmax);
        const float fsc  = __expf(m - mnew);
        m = mnew;
        lsum *= fsc;
        acc *= fsc;

        half4_t pa, pb;
        #pragma unroll
        for (int r = 0; r < 4; ++r) {
            const float p0 = __expf(s0[r] - mnew);
            const float p1 = __expf(s1[r] - mnew);
            lsum += p0 + p1;
            pa[r] = (_Float16)p0;
            pb[r] = (_Float16)p1;
        }

        const half4_t va = __builtin_shufflevector(vv, vv, 0, 1, 2, 3);
        const half4_t vb = __builtin_shufflevector(vv, vv, 4, 5, 6, 7);
        acc = __builtin_amdgcn_mfma_f32_16x16x16f16(va, pa, acc, 0, 0, 0);
        acc = __builtin_amdgcn_mfma_f32_16x16x16f16(vb, pb, acc, 0, 0, 0);
    }

    lsum += __shfl_xor(lsum, 16);
    lsum += __shfl_xor(lsum, 32);
    const float inv = 1.f / lsum;

    float* op = o + ((((size_t)S * Bn + b) * NHh + hd) * HW) * 16;
    f32x4 res;
    #pragma unroll
    for (int r = 0; r < 4; ++r) res[r] = acc[r] * inv;
    *reinterpret_cast<f32x4*>(&op[(size_t)i * 16 + g * 4]) = res;
}

// ---------------------------------------------------------------------------
// Kernel 4: 1x1 output conv (unchanged).
// ---------------------------------------------------------------------------
__global__ __launch_bounds__(256) void out_conv_kernel(
    const float* __restrict__ o, const float* __restrict__ wout,
    const float* __restrict__ bout, float* __restrict__ out)
{
    const int co = blockIdx.x;
    const int sb = blockIdx.y;
    const int tid = threadIdx.x;
    const float* ob = o + (size_t)sb * 64 * HW;

    float acc[4] = {0.f, 0.f, 0.f, 0.f};
    for (int c = 0; c < 64; ++c) {
        const float wv = wout[co * 64 + c];
        #pragma unroll
        for (int p = 0; p < 4; ++p)
            acc[p] = fmaf(wv, ob[(size_t)c * HW + tid + p * 256], acc[p]);
    }
    const float bv = bout[co];
    #pragma unroll
    for (int p = 0; p < 4; ++p)
        out[((size_t)sb * 64 + co) * HW + tid + p * 256] = acc[p] + bv;
}

// ---------------------------------------------------------------------------
extern "C" void kernel_launch(void* const* d_in, const int* in_sizes, int n_in,
                              void* d_out, int out_size, void* d_ws, size_t ws_size,
                              hipStream_t stream)
{
    const float* x1   = (const float*)d_in[0];
    const float* x2   = (const float*)d_in[1];
    const float* x12  = (const float*)d_in[2];
    const float* wq1  = (const float*)d_in[3];
    const float* bq1  = (const float*)d_in[4];
    const float* wq2  = (const float*)d_in[5];
    const float* bq2  = (const float*)d_in[6];
    const float* wq12 = (const float*)d_in[7];
    const float* bq12 = (const float*)d_in[8];
    const float* wout = (const float*)d_in[9];
    const float* bout = (const float*)d_in[10];
    const float* relw = (const float*)d_in[11];
    const float* relh = (const float*)d_in[12];

    float* ws  = (float*)d_ws;
    float* qkv = ws;                                   // 3*8*192*1024
    float* qrw = qkv + (size_t)3 * Bn * CQKV * HW;     // 32*64*1024
    float* qrh = qrw + (size_t)32 * 64 * HW;
    float* o   = qrh + (size_t)32 * 64 * HW;           // 3*8*4*1024*16

    // xt (3.55 MB) and wf (0.66 MB) alias qrw/qrh: they are dead before
    // qrel_kernel writes those buffers (sequential stream order).
    _Float16* xt = (_Float16*)qrw;                     // 24*1156*64 halves
    _Float16* wf = (_Float16*)qrh;                     // 82944*4 halves

    prep_xt_kernel<<<dim3(24, 8), 256, 0, stream>>>(x1, x2, x12, xt);
    prep_wf_kernel<<<dim3(324), 256, 0, stream>>>(wq1, wq2, wq12, wf);

    conv_mfma_kernel<<<dim3(16, 8, 3), 256, 0, stream>>>(
        xt, wf, bq1, bq2, bq12, qkv);

    qrel_kernel<<<dim3(63, 32), 256, 0, stream>>>(qkv, relw, relh, qrw, qrh);

    attn_mfma_kernel<<<dim3(16, 32, 3), 256, 0, stream>>>(qkv, qrw, qrh, o);

    out_conv_kernel<<<dim3(64, 24), 256, 0, stream>>>(o, wout, bout, (float*)d_out);
}